// Round 2
// baseline (5061.246 us; speedup 1.0000x reference)
//
#include <hip/hip_runtime.h>

// T=512, B=64, D=H=1024, gates=4096
#define TT 512
#define NB 64
#define DD 1024
#define NG 4096

typedef __attribute__((ext_vector_type(8))) __bf16 bf16x8;
typedef __attribute__((ext_vector_type(4))) float f32x4;

// workspace layout (bytes)
#define WC_OFF   0ul                       // bf16 [4096][2048]       = 16,777,216
#define HB2_OFF  16777216ul                // u64  [2][64][512] tagged = 524,288
#define BIAS_OFF (HB2_OFF + 524288ul)      // f32  [4096]             = 16,384
#define XBF_OFF  (BIAS_OFF + 16384ul)      // bf16 x mirror           = 67,108,864
#define WS_FULL  (XBF_OFF + 67108864ul)

__device__ __forceinline__ unsigned short f2bf(float f) {
  unsigned int u = __float_as_uint(f);
  u += 0x7fffu + ((u >> 16) & 1u);   // round-to-nearest-even
  return (unsigned short)(u >> 16);
}

__global__ void prep_kernel(const float* __restrict__ x, const float* __restrict__ h0,
                            const float* __restrict__ w_ih, const float* __restrict__ b_ih,
                            const float* __restrict__ w_hh, const float* __restrict__ b_hh,
                            unsigned char* __restrict__ ws, int use_xbf) {
  unsigned short* Wc  = (unsigned short*)(ws + WC_OFF);
  unsigned long long* hb2 = (unsigned long long*)(ws + HB2_OFF);
  float* bias         = (float*)(ws + BIAS_OFF);
  unsigned short* xbf = (unsigned short*)(ws + XBF_OFF);
  long tid = (long)blockIdx.x * blockDim.x + threadIdx.x;
  long stride = (long)gridDim.x * blockDim.x;
  // W_cat[r][k] = k<1024 ? w_ih[r][k] : w_hh[r][k-1024]  (bf16)
  for (long i = tid; i < (long)NG * 2048; i += stride) {
    int r = (int)(i >> 11), k = (int)(i & 2047);
    float v = (k < 1024) ? w_ih[(long)r * 1024 + k] : w_hh[(long)r * 1024 + (k - 1024)];
    Wc[i] = f2bf(v);
  }
  for (long i = tid; i < NG; i += stride) bias[i] = b_ih[i] + b_hh[i];
  // tagged h words: [buf][row 64][word 512]; word = bf16 c0 | bf16 c1 <<16 | tag <<32
  // h_{-1} -> buf1 with tag 0; buf0 zeroed (tag 0 != 1)
  for (long i = tid; i < (long)NB * 512; i += stride) {
    int row = (int)(i >> 9), jc = (int)(i & 511);
    const float* hp = h0 + (long)row * 1024 + jc * 2;
    hb2[32768 + i] = (unsigned long long)f2bf(hp[0]) | ((unsigned long long)f2bf(hp[1]) << 16);
    hb2[i] = 0ull;
  }
  if (use_xbf) {
    for (long i = tid; i < (long)TT * NB * DD; i += stride) xbf[i] = f2bf(x[i]);
  }
}

#define MFMA16 __builtin_amdgcn_mfma_f32_16x16x32_bf16

// 256 wgs (1/CU): bg = blockIdx>>6 (16 batch rows), cg = blockIdx&63 (16 h-cols).
// 8 waves, each owns K-cols [wv*128, wv*128+128) of x AND of h (K=2048 total).
// Weights register-resident. h-exchange is SINGLE-HOP: every 8B word in the h
// buffer is self-validating {2 x bf16 | tag32 = t+1}. No flags, no vmcnt drain:
// the consumer's poll loop loads the tagged words directly; the iteration that
// sees all tags == t IS the data. Reducer tail split across waves 0 (rows 0-7)
// and 1 (rows 8-15): half the LDS reduce reads + half the transcendental chain
// each, publish h before the out store.
// Overwrite safety: a wg publishes h_t (tag t+1, overwriting tag t-1 words) only
// after its step-t barrier, which requires all 8 waves to have seen tags == t
// from all 64 producer wgs of the bg => every wg passed its step t-1 barrier =>
// all reads of tag t-1 data are complete.
__launch_bounds__(512, 2)
__global__ void lstm_kernel(const float* __restrict__ x, const float* __restrict__ c0,
                            float* __restrict__ out, unsigned char* __restrict__ ws,
                            int use_xbf) {
  __shared__ __align__(16) float red[2][8][16][68];  // 69,632 B double-buffered partials
  __shared__ float bias_l[64];

  const unsigned short* Wc   = (const unsigned short*)(ws + WC_OFF);
  unsigned long long* hb2    = (unsigned long long*)(ws + HB2_OFF);  // [2][64][512]
  const float* bias          = (const float*)(ws + BIAS_OFF);
  const unsigned short* xbf  = (const unsigned short*)(ws + XBF_OFF);

  const int tid = threadIdx.x;
  const int bg = blockIdx.x >> 6;
  const int cg = blockIdx.x & 63;
  const int m0 = bg << 4;           // batch base
  const int j0 = cg << 4;           // h-col base
  const int wv = tid >> 6;          // wave 0..7
  const int lane = tid & 63;
  const int ln = lane & 15;
  const int lq = lane >> 4;

  // ---- preload weights into registers (once): wx = x-half K-chunk, wh = h-half ----
  bf16x8 wx[16], wh[16];
  {
    const int kx = wv * 128 + lq * 8;
#pragma unroll
    for (int g = 0; g < 4; ++g) {   // g = gate
      const unsigned short* wp = Wc + (long)(g * 1024 + j0 + ln) * 2048 + kx;
#pragma unroll
      for (int ks = 0; ks < 4; ++ks) {
        wx[g * 4 + ks] = *reinterpret_cast<const bf16x8*>(wp + ks * 32);
        wh[g * 4 + ks] = *reinterpret_cast<const bf16x8*>(wp + 1024 + ks * 32);
      }
    }
  }
  if (tid < 64) bias_l[tid] = bias[(tid >> 4) * 1024 + j0 + (tid & 15)];

  // ---- reducer role (waves 0,1): 2 cells/lane, cell state in registers ----
  const int rrow = ((wv & 1) << 3) + (lane >> 3);   // row 0..15 (wave0: 0-7, wave1: 8-15)
  const int jc   = lane & 7;                        // col pair -> cols 2jc, 2jc+1
  float cr0 = 0.f, cr1 = 0.f;
  if (wv < 2) {
    const float2 cv = *(const float2*)(c0 + (long)(m0 + rrow) * DD + j0 + 2 * jc);
    cr0 = cv.x; cr1 = cv.y;
  }

  // ---- x fragment prefetch (registers, 1 step ahead) ----
  const long xbase = (long)(m0 + ln) * DD + wv * 128 + lq * 8;
  uint4 xcur[4];
  auto load_x = [&](int tt) {
    if (use_xbf) {
      const unsigned short* xp = xbf + (long)tt * (NB * DD) + xbase;
#pragma unroll
      for (int ks = 0; ks < 4; ++ks)
        xcur[ks] = *reinterpret_cast<const uint4*>(xp + ks * 32);
    } else {
      const float* xp = x + (long)tt * (NB * DD) + xbase;
#pragma unroll
      for (int ks = 0; ks < 4; ++ks) {
        float4 f0 = *reinterpret_cast<const float4*>(xp + ks * 32);
        float4 f1 = *reinterpret_cast<const float4*>(xp + ks * 32 + 4);
        uint4 pk;
        pk.x = (unsigned)f2bf(f0.x) | ((unsigned)f2bf(f0.y) << 16);
        pk.y = (unsigned)f2bf(f0.z) | ((unsigned)f2bf(f0.w) << 16);
        pk.z = (unsigned)f2bf(f1.x) | ((unsigned)f2bf(f1.y) << 16);
        pk.w = (unsigned)f2bf(f1.z) | ((unsigned)f2bf(f1.w) << 16);
        xcur[ks] = pk;
      }
    }
  };
  load_x(0);

  // consumer h addressing: lane reads row (m0+ln), col-pairs for 4 frags
  const int hrow = (m0 + ln) * 512 + wv * 64 + lq * 4;   // u64 index within buffer

#pragma unroll 1
  for (int t = 0; t < TT; ++t) {
    const int rb = t & 1;

    // ---- single-hop poll: tagged h words straight to registers ----
    const unsigned long long* hp = hb2 + (((t + 1) & 1) << 15) + hrow;
    const unsigned tgt = (unsigned)t;
    unsigned long long q[16];
    while (true) {
#pragma unroll
      for (int ks = 0; ks < 4; ++ks)
#pragma unroll
        for (int u = 0; u < 4; ++u)
          q[ks * 4 + u] = __hip_atomic_load(hp + ks * 16 + u,
                                            __ATOMIC_RELAXED, __HIP_MEMORY_SCOPE_AGENT);
      bool ok = true;
#pragma unroll
      for (int i = 0; i < 16; ++i) ok &= ((unsigned)(q[i] >> 32) == tgt);
      if (__all(ok)) break;
      __builtin_amdgcn_s_sleep(1);
    }

    // ---- x MFMAs (prefetched regs) ----
    f32x4 a0 = {0.f, 0.f, 0.f, 0.f}, a1 = a0, a2 = a0, a3 = a0;
#pragma unroll
    for (int ks = 0; ks < 4; ++ks) {
      bf16x8 af = __builtin_bit_cast(bf16x8, xcur[ks]);
      a0 = MFMA16(af, wx[ks],      a0, 0, 0, 0);
      a1 = MFMA16(af, wx[4 + ks],  a1, 0, 0, 0);
      a2 = MFMA16(af, wx[8 + ks],  a2, 0, 0, 0);
      a3 = MFMA16(af, wx[12 + ks], a3, 0, 0, 0);
    }
    // non-reducer waves prefetch x for t+1 here (rides across the lgkm-only barrier)
    if (wv >= 2 && t + 1 < TT) load_x(t + 1);

    // ---- h MFMAs (unpack low halves of tagged words) ----
#pragma unroll
    for (int ks = 0; ks < 4; ++ks) {
      uint4 pk;
      pk.x = (unsigned)q[ks * 4 + 0];
      pk.y = (unsigned)q[ks * 4 + 1];
      pk.z = (unsigned)q[ks * 4 + 2];
      pk.w = (unsigned)q[ks * 4 + 3];
      bf16x8 hf = __builtin_bit_cast(bf16x8, pk);
      a0 = MFMA16(hf, wh[ks],      a0, 0, 0, 0);
      a1 = MFMA16(hf, wh[4 + ks],  a1, 0, 0, 0);
      a2 = MFMA16(hf, wh[8 + ks],  a2, 0, 0, 0);
      a3 = MFMA16(hf, wh[12 + ks], a3, 0, 0, 0);
    }

    // ---- write partials (D layout: col=lane&15, row=(lane>>4)*4+r) ----
#pragma unroll
    for (int r = 0; r < 4; ++r) {
      float* rp = &red[rb][wv][lq * 4 + r][ln];
      rp[0] = a0[r]; rp[16] = a1[r]; rp[32] = a2[r]; rp[48] = a3[r];
    }

    // lgkm-only barrier: LDS partials visible; vm prefetch stays in flight
    asm volatile("s_waitcnt lgkmcnt(0)" ::: "memory");
    __builtin_amdgcn_s_barrier();
    __builtin_amdgcn_sched_barrier(0);

    // ---- reduce + cell update + tagged publish (waves 0,1) ----
    if (wv < 2) {
      __builtin_amdgcn_s_setprio(1);
      float s00 = bias_l[2 * jc],      s01 = bias_l[2 * jc + 1];
      float s10 = bias_l[16 + 2 * jc], s11 = bias_l[16 + 2 * jc + 1];
      float s20 = bias_l[32 + 2 * jc], s21 = bias_l[32 + 2 * jc + 1];
      float s30 = bias_l[48 + 2 * jc], s31 = bias_l[48 + 2 * jc + 1];
#pragma unroll
      for (int w = 0; w < 8; ++w) {
        const float* rp = &red[rb][w][rrow][2 * jc];
        float2 v0 = *(const float2*)(rp);
        float2 v1 = *(const float2*)(rp + 16);
        float2 v2 = *(const float2*)(rp + 32);
        float2 v3 = *(const float2*)(rp + 48);
        s00 += v0.x; s01 += v0.y;
        s10 += v1.x; s11 += v1.y;
        s20 += v2.x; s21 += v2.y;
        s30 += v3.x; s31 += v3.y;
      }
      float ig0 = 1.f / (1.f + __expf(-s00)), ig1 = 1.f / (1.f + __expf(-s01));
      float fg0 = 1.f / (1.f + __expf(-s10)), fg1 = 1.f / (1.f + __expf(-s11));
      float gg0 = 1.f - 2.f / (__expf(2.f * s20) + 1.f);
      float gg1 = 1.f - 2.f / (__expf(2.f * s21) + 1.f);
      float og0 = 1.f / (1.f + __expf(-s30)), og1 = 1.f / (1.f + __expf(-s31));
      float cn0 = fg0 * cr0 + ig0 * gg0;
      float cn1 = fg1 * cr1 + ig1 * gg1;
      cr0 = cn0; cr1 = cn1;
      float hv0 = og0 * (1.f - 2.f / (__expf(2.f * cn0) + 1.f));
      float hv1 = og1 * (1.f - 2.f / (__expf(2.f * cn1) + 1.f));

      // publish FIRST (self-validating tagged word, enters fabric earliest)
      unsigned long long pw = (unsigned long long)f2bf(hv0)
        | ((unsigned long long)f2bf(hv1) << 16)
        | ((unsigned long long)(unsigned)(t + 1) << 32);
      __hip_atomic_store(hb2 + ((t & 1) << 15) + (m0 + rrow) * 512 + (j0 >> 1) + jc, pw,
                         __ATOMIC_RELAXED, __HIP_MEMORY_SCOPE_AGENT);

      const long ho = (long)(m0 + rrow) * 1024 + j0 + 2 * jc;
      *(float2*)(out + (long)t * 65536 + ho) = make_float2(hv0, hv1);
      if (t == TT - 1) {
        *(float2*)(out + (long)TT * 65536 + ho) = make_float2(hv0, hv1);
        *(float2*)(out + (long)TT * 65536 + 65536 + ho) = make_float2(cn0, cn1);
      }
      __builtin_amdgcn_s_setprio(0);
      if (t + 1 < TT) load_x(t + 1);   // reducer waves prefetch after publish
    }
  }
}

extern "C" void kernel_launch(void* const* d_in, const int* in_sizes, int n_in,
                              void* d_out, int out_size, void* d_ws, size_t ws_size,
                              hipStream_t stream) {
  const float* x    = (const float*)d_in[0];
  const float* h0   = (const float*)d_in[1];
  const float* c0   = (const float*)d_in[2];
  const float* w_ih = (const float*)d_in[3];
  const float* b_ih = (const float*)d_in[4];
  const float* w_hh = (const float*)d_in[5];
  const float* b_hh = (const float*)d_in[6];
  float* out = (float*)d_out;
  unsigned char* ws = (unsigned char*)d_ws;
  int use_xbf = (ws_size >= WS_FULL) ? 1 : 0;

  hipLaunchKernelGGL(prep_kernel, dim3(2048), dim3(256), 0, stream,
                     x, h0, w_ih, b_ih, w_hh, b_hh, ws, use_xbf);

  void* args[] = { (void*)&x, (void*)&c0, (void*)&out, (void*)&ws, (void*)&use_xbf };
  hipLaunchCooperativeKernel(reinterpret_cast<void*>(lstm_kernel),
                             dim3(256), dim3(512), args, 0, stream);
}

// Round 3
// 2977.002 us; speedup vs baseline: 1.7001x; 1.7001x over previous
//
#include <hip/hip_runtime.h>

// T=512, B=64, D=H=1024, gates=4096
#define TT 512
#define NB 64
#define DD 1024
#define NG 4096

typedef __attribute__((ext_vector_type(8))) __bf16 bf16x8;
typedef __attribute__((ext_vector_type(4))) float f32x4;

// workspace layout (bytes)
#define WC_OFF   0ul                       // bf16 [4096][2048]          = 16,777,216
#define HT_OFF   16777216ul                // bf16 [2][4][64][16][16]    = 262,144 (tile-blocked h)
#define FLG_OFF  (HT_OFF + 262144ul)       // u32  [4][128] flag pairs   = 2,048
#define BIAS_OFF (FLG_OFF + 2048ul)        // f32  [4096]                = 16,384
#define XBF_OFF  (BIAS_OFF + 16384ul)      // bf16 x mirror              = 67,108,864
#define WS_FULL  (XBF_OFF + 67108864ul)

__device__ __forceinline__ unsigned short f2bf(float f) {
  unsigned int u = __float_as_uint(f);
  u += 0x7fffu + ((u >> 16) & 1u);   // round-to-nearest-even
  return (unsigned short)(u >> 16);
}

__global__ void prep_kernel(const float* __restrict__ x, const float* __restrict__ h0,
                            const float* __restrict__ w_ih, const float* __restrict__ b_ih,
                            const float* __restrict__ w_hh, const float* __restrict__ b_hh,
                            unsigned char* __restrict__ ws, int use_xbf) {
  unsigned short* Wc  = (unsigned short*)(ws + WC_OFF);
  unsigned short* ht  = (unsigned short*)(ws + HT_OFF);
  unsigned int* flg   = (unsigned int*)(ws + FLG_OFF);
  float* bias         = (float*)(ws + BIAS_OFF);
  unsigned short* xbf = (unsigned short*)(ws + XBF_OFF);
  long tid = (long)blockIdx.x * blockDim.x + threadIdx.x;
  long stride = (long)gridDim.x * blockDim.x;
  // W_cat[r][k] = k<1024 ? w_ih[r][k] : w_hh[r][k-1024]  (bf16)
  for (long i = tid; i < (long)NG * 2048; i += stride) {
    int r = (int)(i >> 11), k = (int)(i & 2047);
    float v = (k < 1024) ? w_ih[(long)r * 1024 + k] : w_hh[(long)r * 1024 + (k - 1024)];
    Wc[i] = f2bf(v);
  }
  for (long i = tid; i < NG; i += stride) bias[i] = b_ih[i] + b_hh[i];
  // h_{-1} -> tile-blocked buf1: [1][bg][cg][row16][col16]
  for (long i = tid; i < (long)NB * DD; i += stride) {
    int row = (int)(i >> 10), col = (int)(i & 1023);
    int bg = row >> 4, r = row & 15, cg = col >> 4, c = col & 15;
    ht[65536 + ((bg * 64 + cg) * 256 + r * 16 + c)] = f2bf(h0[i]);
  }
  for (long i = tid; i < 512; i += stride) flg[i] = 0;
  if (use_xbf) {
    for (long i = tid; i < (long)TT * NB * DD; i += stride) xbf[i] = f2bf(x[i]);
  }
}

#define MFMA16 __builtin_amdgcn_mfma_f32_16x16x32_bf16

// 256 wgs (1/CU): bg = blockIdx>>6 (16 batch rows), cg = blockIdx&63 (16 h-cols).
// 8 waves, each owns K-cols [wv*128, wv*128+128) of x AND of h (K=2048 fused).
// Weights register/AGPR-resident. h-exchange: tile-blocked buffer (each producer
// wg owns 8 full cachelines, no false sharing), flag-based sync (poll = one u64
// load per lane covering both reducer-wave flags of one producer). Tail split
// across waves 0 (rows 0-7) and 1 (rows 8-15); each publishes its half-tile,
// drains ONLY its h stores (vmcnt 0), sets its flag, THEN stores out (out-store
// latency off the critical chain).
// Overwrite safety: wg publishes h_t into buf[t&1] (overwriting h_{t-2}) only
// after its step-t barrier; the barrier requires all 8 waves to have passed
// their polls (collectively all 64 producers' flags >= t), i.e. every wg of the
// bg passed its step t-1 barrier, i.e. all reads of h_{t-2} are complete.
__launch_bounds__(512, 2)
__global__ void lstm_kernel(const float* __restrict__ x, const float* __restrict__ c0,
                            float* __restrict__ out, unsigned char* __restrict__ ws,
                            int use_xbf) {
  __shared__ __align__(16) float red[2][8][16][68];  // 69,632 B double-buffered partials
  __shared__ float bias_l[64];

  const unsigned short* Wc  = (const unsigned short*)(ws + WC_OFF);
  unsigned long long* hbq   = (unsigned long long*)(ws + HT_OFF);   // u64 view, 16384/buf
  unsigned int* hb32        = (unsigned int*)(ws + HT_OFF);         // u32 view, 32768/buf
  const unsigned long long* flgq = (const unsigned long long*)(ws + FLG_OFF);
  unsigned int* flg         = (unsigned int*)(ws + FLG_OFF);
  const float* bias         = (const float*)(ws + BIAS_OFF);
  const unsigned short* xbf = (const unsigned short*)(ws + XBF_OFF);

  const int tid = threadIdx.x;
  const int bg = blockIdx.x >> 6;
  const int cg = blockIdx.x & 63;
  const int m0 = bg << 4;           // batch base
  const int j0 = cg << 4;           // h-col base
  const int wv = tid >> 6;          // wave 0..7
  const int lane = tid & 63;
  const int ln = lane & 15;
  const int lq = lane >> 4;

  // ---- preload weights (once): wx = x-half K-chunk, wh = h-half ----
  bf16x8 wx[16], wh[16];
  {
    const int kx = wv * 128 + lq * 8;
#pragma unroll
    for (int g = 0; g < 4; ++g) {   // g = gate
      const unsigned short* wp = Wc + (long)(g * 1024 + j0 + ln) * 2048 + kx;
#pragma unroll
      for (int ks = 0; ks < 4; ++ks) {
        wx[g * 4 + ks] = *reinterpret_cast<const bf16x8*>(wp + ks * 32);
        wh[g * 4 + ks] = *reinterpret_cast<const bf16x8*>(wp + 1024 + ks * 32);
      }
    }
  }
  if (tid < 64) bias_l[tid] = bias[(tid >> 4) * 1024 + j0 + (tid & 15)];

  // ---- reducer role (waves 0,1): 2 cells/lane, cell state in registers ----
  const int rrow = ((wv & 1) << 3) + (lane >> 3);   // wave0: rows 0-7, wave1: 8-15
  const int jc   = lane & 7;                        // col pair -> cols 2jc, 2jc+1
  float cr0 = 0.f, cr1 = 0.f;
  if (wv < 2) {
    const float2 cv = *(const float2*)(c0 + (long)(m0 + rrow) * DD + j0 + 2 * jc);
    cr0 = cv.x; cr1 = cv.y;
  }

  // ---- x fragment prefetch (registers, 1 step ahead) ----
  const long xbase = (long)(m0 + ln) * DD + wv * 128 + lq * 8;
  uint4 xcur[4];
  auto load_x = [&](int tt) {
    if (use_xbf) {
      const unsigned short* xp = xbf + (long)tt * (NB * DD) + xbase;
#pragma unroll
      for (int ks = 0; ks < 4; ++ks)
        xcur[ks] = *reinterpret_cast<const uint4*>(xp + ks * 32);
    } else {
      const float* xp = x + (long)tt * (NB * DD) + xbase;
#pragma unroll
      for (int ks = 0; ks < 4; ++ks) {
        float4 f0 = *reinterpret_cast<const float4*>(xp + ks * 32);
        float4 f1 = *reinterpret_cast<const float4*>(xp + ks * 32 + 4);
        uint4 pk;
        pk.x = (unsigned)f2bf(f0.x) | ((unsigned)f2bf(f0.y) << 16);
        pk.y = (unsigned)f2bf(f0.z) | ((unsigned)f2bf(f0.w) << 16);
        pk.z = (unsigned)f2bf(f1.x) | ((unsigned)f2bf(f1.y) << 16);
        pk.w = (unsigned)f2bf(f1.z) | ((unsigned)f2bf(f1.w) << 16);
        xcur[ks] = pk;
      }
    }
  };
  load_x(0);

  // consumer h addressing (u64 units): frag ks reads tile cg' = wv*8+2ks+(lq>>1),
  // row ln, col (lq&1)*8 -> two u64
  int qoff[4];
#pragma unroll
  for (int ks = 0; ks < 4; ++ks)
    qoff[ks] = ((bg * 64 + wv * 8 + 2 * ks + (lq >> 1)) * 64) + ln * 4 + (lq & 1) * 2;
  // poll address (u64 covering both flags of one producer)
  const int foff = bg * 64 + wv * 8 + (lane & 7);

#pragma unroll 1
  for (int t = 0; t < TT; ++t) {
    const int rb = t & 1;

    // ---- wait for my 8 producers (both reducer waves each) ----
    if (t > 0) {
      const unsigned tgt = (unsigned)t;
      while (true) {
        unsigned long long v = __hip_atomic_load(flgq + foff, __ATOMIC_RELAXED,
                                                 __HIP_MEMORY_SCOPE_AGENT);
        bool ok = ((unsigned)v >= tgt) && ((unsigned)(v >> 32) >= tgt);
        if (__all(ok)) break;
        __builtin_amdgcn_s_sleep(1);
      }
    }
    asm volatile("" ::: "memory");   // no hoisting of h loads above the poll

    // ---- issue h fragment loads (device-scope u64, straight to registers) ----
    const unsigned long long* hp = hbq + (((t + 1) & 1) << 14);
    unsigned long long q[8];
#pragma unroll
    for (int ks = 0; ks < 4; ++ks) {
      q[2 * ks]     = __hip_atomic_load(hp + qoff[ks],     __ATOMIC_RELAXED, __HIP_MEMORY_SCOPE_AGENT);
      q[2 * ks + 1] = __hip_atomic_load(hp + qoff[ks] + 1, __ATOMIC_RELAXED, __HIP_MEMORY_SCOPE_AGENT);
    }

    // ---- x MFMAs (prefetched regs; hide h-load latency) ----
    f32x4 a0 = {0.f, 0.f, 0.f, 0.f}, a1 = a0, a2 = a0, a3 = a0;
#pragma unroll
    for (int ks = 0; ks < 4; ++ks) {
      bf16x8 af = __builtin_bit_cast(bf16x8, xcur[ks]);
      a0 = MFMA16(af, wx[ks],      a0, 0, 0, 0);
      a1 = MFMA16(af, wx[4 + ks],  a1, 0, 0, 0);
      a2 = MFMA16(af, wx[8 + ks],  a2, 0, 0, 0);
      a3 = MFMA16(af, wx[12 + ks], a3, 0, 0, 0);
    }
    // non-reducer waves prefetch x for t+1 (rides across the lgkm-only barrier)
    if (wv >= 2 && t + 1 < TT) load_x(t + 1);

    // ---- h MFMAs ----
#pragma unroll
    for (int ks = 0; ks < 4; ++ks) {
      union { unsigned long long qq[2]; bf16x8 v; } uu;
      uu.qq[0] = q[2 * ks]; uu.qq[1] = q[2 * ks + 1];
      a0 = MFMA16(uu.v, wh[ks],      a0, 0, 0, 0);
      a1 = MFMA16(uu.v, wh[4 + ks],  a1, 0, 0, 0);
      a2 = MFMA16(uu.v, wh[8 + ks],  a2, 0, 0, 0);
      a3 = MFMA16(uu.v, wh[12 + ks], a3, 0, 0, 0);
    }

    // ---- write partials (D layout: col=lane&15, row=(lane>>4)*4+r) ----
#pragma unroll
    for (int r = 0; r < 4; ++r) {
      float* rp = &red[rb][wv][lq * 4 + r][ln];
      rp[0] = a0[r]; rp[16] = a1[r]; rp[32] = a2[r]; rp[48] = a3[r];
    }

    // lgkm-only barrier: LDS partials visible; vm prefetch stays in flight
    asm volatile("s_waitcnt lgkmcnt(0)" ::: "memory");
    __builtin_amdgcn_s_barrier();
    __builtin_amdgcn_sched_barrier(0);

    // ---- reduce + cell update + publish (waves 0,1) ----
    if (wv < 2) {
      __builtin_amdgcn_s_setprio(1);
      float s00 = bias_l[2 * jc],      s01 = bias_l[2 * jc + 1];
      float s10 = bias_l[16 + 2 * jc], s11 = bias_l[16 + 2 * jc + 1];
      float s20 = bias_l[32 + 2 * jc], s21 = bias_l[32 + 2 * jc + 1];
      float s30 = bias_l[48 + 2 * jc], s31 = bias_l[48 + 2 * jc + 1];
#pragma unroll
      for (int w = 0; w < 8; ++w) {
        const float* rp = &red[rb][w][rrow][2 * jc];
        float2 v0 = *(const float2*)(rp);
        float2 v1 = *(const float2*)(rp + 16);
        float2 v2 = *(const float2*)(rp + 32);
        float2 v3 = *(const float2*)(rp + 48);
        s00 += v0.x; s01 += v0.y;
        s10 += v1.x; s11 += v1.y;
        s20 += v2.x; s21 += v2.y;
        s30 += v3.x; s31 += v3.y;
      }
      float ig0 = 1.f / (1.f + __expf(-s00)), ig1 = 1.f / (1.f + __expf(-s01));
      float fg0 = 1.f / (1.f + __expf(-s10)), fg1 = 1.f / (1.f + __expf(-s11));
      float gg0 = 1.f - 2.f / (__expf(2.f * s20) + 1.f);
      float gg1 = 1.f - 2.f / (__expf(2.f * s21) + 1.f);
      float og0 = 1.f / (1.f + __expf(-s30)), og1 = 1.f / (1.f + __expf(-s31));
      float cn0 = fg0 * cr0 + ig0 * gg0;
      float cn1 = fg1 * cr1 + ig1 * gg1;
      cr0 = cn0; cr1 = cn1;
      float hv0 = og0 * (1.f - 2.f / (__expf(2.f * cn0) + 1.f));
      float hv1 = og1 * (1.f - 2.f / (__expf(2.f * cn1) + 1.f));

      // publish this wave's half-tile word (2 bf16), drain, flag — BEFORE out
      unsigned int pw = (unsigned)f2bf(hv0) | ((unsigned)f2bf(hv1) << 16);
      __hip_atomic_store(hb32 + (rb << 15) + (bg * 64 + cg) * 128 + rrow * 8 + jc, pw,
                         __ATOMIC_RELAXED, __HIP_MEMORY_SCOPE_AGENT);
      asm volatile("s_waitcnt vmcnt(0)" ::: "memory");   // this wave's h stores at L3
      if (lane == 0)
        __hip_atomic_store(flg + bg * 128 + 2 * cg + wv, (unsigned)(t + 1),
                           __ATOMIC_RELAXED, __HIP_MEMORY_SCOPE_AGENT);

      const long ho = (long)(m0 + rrow) * 1024 + j0 + 2 * jc;
      *(float2*)(out + (long)t * 65536 + ho) = make_float2(hv0, hv1);
      if (t == TT - 1) {
        *(float2*)(out + (long)TT * 65536 + ho) = make_float2(hv0, hv1);
        *(float2*)(out + (long)TT * 65536 + 65536 + ho) = make_float2(cn0, cn1);
      }
      __builtin_amdgcn_s_setprio(0);
      if (t + 1 < TT) load_x(t + 1);   // reducer waves prefetch after publish
    }
  }
}

extern "C" void kernel_launch(void* const* d_in, const int* in_sizes, int n_in,
                              void* d_out, int out_size, void* d_ws, size_t ws_size,
                              hipStream_t stream) {
  const float* x    = (const float*)d_in[0];
  const float* h0   = (const float*)d_in[1];
  const float* c0   = (const float*)d_in[2];
  const float* w_ih = (const float*)d_in[3];
  const float* b_ih = (const float*)d_in[4];
  const float* w_hh = (const float*)d_in[5];
  const float* b_hh = (const float*)d_in[6];
  float* out = (float*)d_out;
  unsigned char* ws = (unsigned char*)d_ws;
  int use_xbf = (ws_size >= WS_FULL) ? 1 : 0;

  hipLaunchKernelGGL(prep_kernel, dim3(2048), dim3(256), 0, stream,
                     x, h0, w_ih, b_ih, w_hh, b_hh, ws, use_xbf);

  void* args[] = { (void*)&x, (void*)&c0, (void*)&out, (void*)&ws, (void*)&use_xbf };
  hipLaunchCooperativeKernel(reinterpret_cast<void*>(lstm_kernel),
                             dim3(256), dim3(512), args, 0, stream);
}